// Round 1
// 689.296 us; speedup vs baseline: 1.0868x; 1.0868x over previous
//
#include <hip/hip_runtime.h>

#define D_  128
#define DH_ 32

typedef __attribute__((ext_vector_type(8))) short bf16x8;  // MFMA A/B frag (4 VGPRs)
typedef __attribute__((ext_vector_type(4))) float f32x4;   // MFMA C/D frag

__device__ __forceinline__ short f2bf(float f) {
    // round-to-nearest-even fp32 -> bf16
    unsigned u = __float_as_uint(f);
    unsigned r = (u + 0x7FFF + ((u >> 16) & 1)) >> 16;
    return (short)r;
}

typedef __attribute__((address_space(1))) const void gvoid_t;
typedef __attribute__((address_space(3))) void svoid_t;

__device__ __forceinline__ void gload_lds16(const float* g, float* l) {
    // async global->LDS, 16B per lane; LDS dest = wave-uniform base + lane*16
    __builtin_amdgcn_global_load_lds((gvoid_t*)g, (svoid_t*)l, 16, 0, 0);
}

// Fused single-x-read kernel. Each 512-thread block owns 128 rows; each wave
// owns 16 rows, stages them once into LDS (XOR-swizzled via pre-swizzled
// global source, linear LDS dest), computes MFMA scores from LDS, then does
// the per-segment weighted accumulation from the SAME LDS copy (fp32).
// Entirely wave-local: no __syncthreads anywhere.
// out layout: [0, P*128)     = numerator accumulators (atomic)
//             [P*128, P*129) = denominator accumulators (atomic), later pids
__global__ __launch_bounds__(512, 4) void tap_main(
    const float* __restrict__ x,
    const int*   __restrict__ pid,
    const float* __restrict__ W1,
    const float* __restrict__ b1,
    const float* __restrict__ W2,
    const float* __restrict__ b2,
    float* __restrict__ out,
    int N, int P)
{
    __shared__ float xs[128 * D_];      // 64 KB: 128 rows x 512B, swizzled

    const int tid  = threadIdx.x;
    const int lane = tid & 63;
    const int wave = tid >> 6;          // 0..7
    const int lb   = wave * 16;         // wave's local row base
    const int row0 = blockIdx.x * 128;
    const int R0   = row0 + lb;         // wave's global row base

    const int n16  = lane & 15;         // m (A row) / n (B,D col) index
    const int quad = lane >> 4;         // k-group

    // ---- async stage: this wave's 16 rows (8 KB) into LDS ----
    // LDS[row][d] = x[row][d ^ swz(row)], swz(row) = (row&31)<<4 (byte XOR).
    // Source address carries the swizzle (global src is per-lane); LDS dest
    // stays linear (global_load_lds requirement).
    {
        const int slot = lane & 31;     // 16B slot within a 512B row
        const int half = lane >> 5;     // which of the round's 2 rows
        #pragma unroll
        for (int t = 0; t < 8; ++t) {
            int lr = lb + t * 2 + half;
            int gr = R0 + t * 2 + half; if (gr > N - 1) gr = N - 1;
            unsigned sb = ((unsigned)(slot * 16)) ^ ((unsigned)((lr & 31) << 4));
            gload_lds16(x + (size_t)gr * D_ + (sb >> 2),
                        xs + (size_t)(lb + t * 2) * D_);
        }
    }

    // pids for this wave's 16 rows live in lanes 0..15 (shfl'd later)
    int pr;
    { int gr = R0 + n16; if (gr > N - 1) gr = N - 1; pr = pid[gr]; }

    // ---- B fragments: W1[k][j] from global (16 KB, L1/L2-cached) ----
    bf16x8 bfrag[4][2];
    #pragma unroll
    for (int kt = 0; kt < 4; ++kt)
        #pragma unroll
        for (int jt = 0; jt < 2; ++jt) {
            const float* wp = W1 + (kt * 32 + quad * 8) * DH_ + jt * 16 + n16;
            #pragma unroll
            for (int i = 0; i < 8; ++i) bfrag[kt][jt][i] = f2bf(wp[i * DH_]);
        }

    f32x4 acc[2] = {};                  // [jt]; D row = quad*4+reg, col = n16

    // drain this wave's own staging loads (wave-local, no barrier)
    asm volatile("s_waitcnt vmcnt(0)" ::: "memory");

    // ---- MFMA: h = x @ W1, A-frags from swizzled LDS ----
    const int lr_a = lb + n16;                       // this lane's A row
    const unsigned swz_a = (unsigned)((lr_a & 31) << 4);
    const char* xrow = (const char*)xs + (size_t)lr_a * (D_ * 4);
    #pragma unroll
    for (int kt = 0; kt < 4; ++kt) {
        unsigned b0 = (unsigned)(kt * 128 + quad * 32);
        float4 v0 = *(const float4*)(xrow + (b0 ^ swz_a));
        float4 v1 = *(const float4*)(xrow + ((b0 + 16) ^ swz_a));
        bf16x8 af;
        af[0] = f2bf(v0.x); af[1] = f2bf(v0.y);
        af[2] = f2bf(v0.z); af[3] = f2bf(v0.w);
        af[4] = f2bf(v1.x); af[5] = f2bf(v1.y);
        af[6] = f2bf(v1.z); af[7] = f2bf(v1.w);
        #pragma unroll
        for (int jt = 0; jt < 2; ++jt)
            acc[jt] = __builtin_amdgcn_mfma_f32_16x16x32_bf16(
                af, bfrag[kt][jt], acc[jt], 0, 0, 0);
    }

    // ---- epilogue: e[q] = exp(tanh(h+b1)@W2 + b2), all lanes redundant ----
    const float b2v = b2[0];
    float w2v[2], b1v[2];
    #pragma unroll
    for (int jt = 0; jt < 2; ++jt) {
        w2v[jt] = W2[jt * 16 + n16];
        b1v[jt] = b1[jt * 16 + n16];
    }

    float e[4];
    #pragma unroll
    for (int q = 0; q < 4; ++q) {
        float s = 0.f;
        #pragma unroll
        for (int jt = 0; jt < 2; ++jt) {
            float h = acc[jt][q] + b1v[jt];
            h = fminf(fmaxf(h, -15.f), 15.f);
            float z = __expf(2.f * h);          // tanh via exp
            float t = 1.f - 2.f / (z + 1.f);
            s = fmaf(t, w2v[jt], s);
        }
        // reduce over the 16 j-lanes (xor masks stay within the quad group)
        s += __shfl_xor(s, 1);
        s += __shfl_xor(s, 2);
        s += __shfl_xor(s, 4);
        s += __shfl_xor(s, 8);
        int gr = R0 + quad * 4 + q;             // row this e belongs to
        e[q] = (gr < N) ? __expf(s + b2v) : 0.f;  // bounded |s|<~6
    }

    // ---- Phase B: per-wave segment accumulation from LDS (fp32) ----
    // lane = feature pair (2*lane, 2*lane+1); rows walked sequentially.
    float a0 = 0.f, a1 = 0.f, ad = 0.f;
    int   cur = __shfl(pr, 0);
    #pragma unroll
    for (int r = 0; r < 16; ++r) {
        int sg = __shfl(pr, r);                  // wave-uniform
        if (sg != cur) {
            atomicAdd(&out[cur * D_ + 2 * lane],     a0);
            atomicAdd(&out[cur * D_ + 2 * lane + 1], a1);
            if (lane == 0) atomicAdd(&out[P * D_ + cur], ad);
            a0 = a1 = ad = 0.f;
            cur = sg;
        }
        // e for row r: held by quad group r>>2, register r&3
        float ev = __shfl(e[r & 3], (r >> 2) << 4);
        int lr = lb + r;
        unsigned swz = (unsigned)((lr & 31) << 4);
        const float2 xv = *(const float2*)(
            (const char*)xs + (size_t)lr * (D_ * 4) + (((unsigned)(lane * 8)) ^ swz));
        a0 = fmaf(ev, xv.x, a0);
        a1 = fmaf(ev, xv.y, a1);
        ad += ev;
    }
    atomicAdd(&out[cur * D_ + 2 * lane],     a0);
    atomicAdd(&out[cur * D_ + 2 * lane + 1], a1);
    if (lane == 0) atomicAdd(&out[P * D_ + cur], ad);
}

// Divide by denominator (0 -> 1, matches reference guard), then overwrite
// denominator slot with float(pid).
__global__ __launch_bounds__(128) void tap_finalize(float* __restrict__ out, int P)
{
    const int p = blockIdx.x;
    const int f = threadIdx.x;     // 128 threads
    float den = out[P * D_ + p];
    den = (den == 0.f) ? 1.f : den;
    float v = out[p * D_ + f];
    __syncthreads();               // all reads of den slot done before overwrite
    out[p * D_ + f] = v / den;
    if (f == 0) out[P * D_ + p] = (float)p;
}

extern "C" void kernel_launch(void* const* d_in, const int* in_sizes, int n_in,
                              void* d_out, int out_size, void* d_ws, size_t ws_size,
                              hipStream_t stream)
{
    const float* x   = (const float*)d_in[0];
    const int*   pid = (const int*)d_in[1];
    const float* W1  = (const float*)d_in[2];
    const float* b1  = (const float*)d_in[3];
    const float* W2  = (const float*)d_in[4];
    const float* b2  = (const float*)d_in[5];
    float* out = (float*)d_out;

    const int N = in_sizes[0] / D_;          // 1,000,000
    const int P = out_size / (D_ + 1);       // 16,384

    hipMemsetAsync(d_out, 0, (size_t)out_size * sizeof(float), stream);

    const int blocks = (N + 127) / 128;      // 128 rows per 512-thread block
    tap_main<<<blocks, 512, 0, stream>>>(x, pid, W1, b1, W2, b2, out, N, P);
    tap_finalize<<<P, 128, 0, stream>>>(out, P);
}